// Round 1
// baseline (658.060 us; speedup 1.0000x reference)
//
#include <hip/hip_runtime.h>

#define NATOMS 768
#define NM1    767
#define NEDGE  (768*767)       // 589056
#define DIM    64
#define NC     50
#define GAPF   (5.0f/49.0f)    // linspace(0,5,50) spacing
#define NEG_INV_GAP (-49.0f/5.0f)  // -1/gap = -9.8

// softplus_bt(x, beta=0.5, thr=14): bx>thr ? x : log1p(exp(bx))/beta
__device__ __forceinline__ float softplus05(float x) {
    float bx = 0.5f * x;
    return (bx > 14.0f) ? x : 2.0f * __logf(1.0f + __expf(bx));
}

// ---------------- embedding gather ----------------
__global__ __launch_bounds__(256)
void k_embed(const int* __restrict__ types, const float* __restrict__ emb,
             float* __restrict__ h) {
    int idx = blockIdx.x * 256 + threadIdx.x;        // < 768*64
    int i = idx >> 6, d = idx & 63;
    h[idx] = emb[types[i] * DIM + d];
}

// ---------------- nw = h @ w1[l]  (no bias) ----------------
__global__ __launch_bounds__(256)
void k_nodew(const float* __restrict__ h, const float* __restrict__ w,
             float* __restrict__ nw) {
    int row = blockIdx.x * 4 + (threadIdx.x >> 6);
    int d = threadIdx.x & 63;
    const float* hr = h + row * DIM;
    float acc = 0.0f;
    #pragma unroll 8
    for (int k = 0; k < DIM; ++k) acc = fmaf(hr[k], w[k * DIM + d], acc);
    nw[row * DIM + d] = acc;
}

// ---------------- edge MLP + gather-mul + segment-sum ----------------
// dst-major: block (j, q) handles sources i in [q*256, q*256+256) for dest j.
// One wave per block; lane = edge within 64-edge batch. Writes partial
// agg into aggp[q][j][ch]; k_update sums the 3 partials.
__global__ __launch_bounds__(64)
void k_edge_agg(const float* __restrict__ dist, const float* __restrict__ nw,
                const float* __restrict__ pw1, const float* __restrict__ pb1,
                const float* __restrict__ pw2, const float* __restrict__ pb2,
                float* __restrict__ aggp) {
    __shared__ float ts[64 * 65];      // padded: all phases conflict-free
    const int lane  = threadIdx.x;     // 0..63
    const int j     = blockIdx.x / 3;
    const int q     = blockIdx.x % 3;
    const int ibase = q * 256;

    float csum = 0.0f;                 // partial agg[j][lane]

    for (int b = 0; b < 4; ++b) {
        const int  rowbase = ibase + b * 64;
        const int  i       = rowbase + lane;
        const bool valid   = (i != j);
        // edge (i,j) index: i*767 + (j - (j>i)); clamp invalid lane to 0
        const int eidx = valid ? (i * NM1 + (j - (j > i))) : 0;
        const float de = dist[eidx];

        // ---- layer 1: t1[d] = pb1[d] + sum_k rbf_k * pw1[k][d] ----
        float t1[DIM];
        #pragma unroll
        for (int d = 0; d < DIM; ++d) t1[d] = pb1[d];
        for (int k = 0; k < NC; ++k) {
            float x  = de - GAPF * (float)k;
            float rk = __expf(NEG_INV_GAP * x * x);
            #pragma unroll
            for (int d = 0; d < DIM; ++d)
                t1[d] = fmaf(rk, pw1[k * DIM + d], t1[d]);
        }
        // softplus(beta=0.5, thr=14), stash to lane-private LDS row
        #pragma unroll
        for (int d = 0; d < DIM; ++d) ts[lane * 65 + d] = softplus05(t1[d]);

        // ---- layer 2: o[d] = pb2[d] + sum_k t[k] * pw2[k][d] ----
        // (reads back own LDS row -> dynamic k-loop, no giant unroll)
        float o[DIM];
        #pragma unroll
        for (int d = 0; d < DIM; ++d) o[d] = pb2[d];
        for (int k = 0; k < DIM; ++k) {
            float tk = ts[lane * 65 + k];
            #pragma unroll
            for (int d = 0; d < DIM; ++d)
                o[d] = fmaf(tk, pw2[k * DIM + d], o[d]);
        }

        // overwrite own row with (masked) edge vector
        const float sc = valid ? 1.0f : 0.0f;
        #pragma unroll
        for (int d = 0; d < DIM; ++d) ts[lane * 65 + d] = sc * o[d];
        __syncthreads();

        // column reduce: lane = channel; msg = e * nw[src] fused here,
        // nw loads are fully coalesced across lanes.
        #pragma unroll 8
        for (int e = 0; e < 64; ++e)
            csum = fmaf(ts[e * 65 + lane], nw[(rowbase + e) * DIM + lane], csum);
        __syncthreads();
    }
    aggp[(q * NATOMS + j) * DIM + lane] = csum;
}

// ---------------- h += softplus(agg@qw1+qb1)@qw2 + qb2 ----------------
__global__ __launch_bounds__(64)
void k_update(const float* __restrict__ aggp,
              const float* __restrict__ qw1, const float* __restrict__ qb1,
              const float* __restrict__ qw2, const float* __restrict__ qb2,
              float* __restrict__ h) {
    __shared__ float ts[DIM];
    const int i = blockIdx.x;
    const int d = threadIdx.x;
    float t = qb1[d];
    #pragma unroll 8
    for (int k = 0; k < DIM; ++k) {
        float a = aggp[i * DIM + k]
                + aggp[(NATOMS + i) * DIM + k]
                + aggp[(2 * NATOMS + i) * DIM + k];
        t = fmaf(a, qw1[k * DIM + d], t);
    }
    ts[d] = softplus05(t);
    __syncthreads();
    float o = qb2[d];
    #pragma unroll 8
    for (int k = 0; k < DIM; ++k) o = fmaf(ts[k], qw2[k * DIM + d], o);
    h[i * DIM + d] += o;
}

// ---------------- ha = (ShiftSoftplus(h@au_w1+au_b1)) @ au_w2 + au_b2 ----------------
__global__ __launch_bounds__(256)
void k_atomout(const float* __restrict__ h,
               const float* __restrict__ w1, const float* __restrict__ b1,
               const float* __restrict__ w2, const float* __restrict__ b2,
               float* __restrict__ ha) {
    const int lane = threadIdx.x & 63;
    const int i = blockIdx.x * 4 + (threadIdx.x >> 6);
    float t = b1[lane];
    #pragma unroll 8
    for (int k = 0; k < DIM; ++k) t = fmaf(h[i * DIM + k], w1[k * DIM + lane], t);
    // beta=1, thr=20, shift=log(2)
    t = ((t > 20.0f) ? t : __logf(1.0f + __expf(t))) - 0.693147180559945f;
    float v = t * w2[lane];
    #pragma unroll
    for (int s = 32; s > 0; s >>= 1) v += __shfl_down(v, s, 64);
    if (lane == 0) ha[i] = v + b2[0];
}

// ---------------- readout over all edges + softmax ----------------
__global__ __launch_bounds__(256)
void k_readout(const float* __restrict__ dist, const int* __restrict__ src,
               const int* __restrict__ dst, const float* __restrict__ ha,
               const float* __restrict__ w1, const float* __restrict__ b1,
               const float* __restrict__ w2, const float* __restrict__ b2,
               float* __restrict__ out) {
    const int e = blockIdx.x * 256 + threadIdx.x;    // grid*block == NEDGE exactly
    const float de = dist[e];
    const float fa = ha[src[e]];
    const float fb = ha[dst[e]];
    float hid[DIM];
    #pragma unroll
    for (int d = 0; d < DIM; ++d)
        hid[d] = fmaf(fb, w1[DIM + d], fmaf(fa, w1[d], b1[d]));
    for (int k = 0; k < NC; ++k) {
        float x  = de - GAPF * (float)k;
        float rk = __expf(NEG_INV_GAP * x * x);
        #pragma unroll
        for (int d = 0; d < DIM; ++d)
            hid[d] = fmaf(rk, w1[(2 + k) * DIM + d], hid[d]);
    }
    float l0 = b2[0], l1 = b2[1];
    #pragma unroll
    for (int d = 0; d < DIM; ++d) {
        float hv = fmaxf(hid[d], 0.0f);
        l0 = fmaf(hv, w2[2 * d], l0);
        l1 = fmaf(hv, w2[2 * d + 1], l1);
    }
    float m = fmaxf(l0, l1);
    float e0 = __expf(l0 - m), e1 = __expf(l1 - m);
    float inv = 1.0f / (e0 + e1);
    float2 r; r.x = e0 * inv; r.y = e1 * inv;
    reinterpret_cast<float2*>(out)[e] = r;
}

extern "C" void kernel_launch(void* const* d_in, const int* in_sizes, int n_in,
                              void* d_out, int out_size, void* d_ws, size_t ws_size,
                              hipStream_t stream) {
    const int*   types = (const int*)d_in[0];
    const float* dist  = (const float*)d_in[1];
    const int*   src   = (const int*)d_in[2];
    const int*   dst   = (const int*)d_in[3];
    const float* emb   = (const float*)d_in[4];
    const float* w1    = (const float*)d_in[5];
    const float* pw1   = (const float*)d_in[6];
    const float* pb1   = (const float*)d_in[7];
    const float* pw2   = (const float*)d_in[8];
    const float* pb2   = (const float*)d_in[9];
    const float* qw1   = (const float*)d_in[10];
    const float* qb1   = (const float*)d_in[11];
    const float* qw2   = (const float*)d_in[12];
    const float* qb2   = (const float*)d_in[13];
    const float* auw1  = (const float*)d_in[14];
    const float* aub1  = (const float*)d_in[15];
    const float* auw2  = (const float*)d_in[16];
    const float* aub2  = (const float*)d_in[17];
    const float* row1  = (const float*)d_in[18];
    const float* rob1  = (const float*)d_in[19];
    const float* row2  = (const float*)d_in[20];
    const float* rob2  = (const float*)d_in[21];

    float* h    = (float*)d_ws;             // 768*64
    float* nw   = h + NATOMS * DIM;         // 768*64
    float* aggp = nw + NATOMS * DIM;        // 3 * 768*64 partials
    float* ha   = aggp + 3 * NATOMS * DIM;  // 768
    float* outp = (float*)d_out;

    k_embed<<<192, 256, 0, stream>>>(types, emb, h);
    for (int l = 0; l < 3; ++l) {
        k_nodew<<<192, 256, 0, stream>>>(h, w1 + l * DIM * DIM, nw);
        k_edge_agg<<<2304, 64, 0, stream>>>(dist, nw,
            pw1 + l * NC * DIM, pb1 + l * DIM,
            pw2 + l * DIM * DIM, pb2 + l * DIM, aggp);
        k_update<<<768, 64, 0, stream>>>(aggp,
            qw1 + l * DIM * DIM, qb1 + l * DIM,
            qw2 + l * DIM * DIM, qb2 + l * DIM, h);
    }
    k_atomout<<<192, 256, 0, stream>>>(h, auw1, aub1, auw2, aub2, ha);
    k_readout<<<2301, 256, 0, stream>>>(dist, src, dst, ha,
                                        row1, rob1, row2, rob2, outp);
}

// Round 2
// 257.266 us; speedup vs baseline: 2.5579x; 2.5579x over previous
//
#include <hip/hip_runtime.h>

#define NATOMS 768
#define NM1    767
#define NEDGE  (768*767)       // 589056
#define DIM    64
#define NC     50
#define GAPF   (5.0f/49.0f)    // center spacing (linspace(0,5,50))
#define NIGAP  (-49.0f/5.0f)   // -1/gap
#define G      1024            // table resolution
#define STEPF  (5.0f/1023.0f)
#define INVSTEP (1023.0f/5.0f)
#define LN2F   0.693147180559945f

// ws layout (float offsets), all 256-float aligned
#define WS_H     0              // 768*64
#define WS_NW    49152          // 768*64
#define WS_AGGP  98304          // 8*768*64
#define WS_HA    491520         // 768 (+pad)
#define WS_DISTT 492288         // 768*768
#define WS_TT    1082112        // 4 tables * 1024*64 float2 = 524288 floats

__device__ __forceinline__ float softplus05(float x) {
    float bx = 0.5f * x;
    return (bx > 14.0f) ? x : 2.0f * __logf(1.0f + __expf(bx));
}

// ============ prologue: tables + embed/nodew0 + dist transpose ============
// blocks [0,1024): 4 tables x 1024 g, wave per (tbl,g)
// blocks [1024,1216): embed + nodew layer0, wave per atom
// blocks [1216,3520): distT[j][i] transpose (diag = 0)
__global__ __launch_bounds__(256)
void k_pre(const int* __restrict__ types, const float* __restrict__ dist,
           const float* __restrict__ emb, const float* __restrict__ w1all,
           const float* __restrict__ pw1, const float* __restrict__ pb1,
           const float* __restrict__ pw2, const float* __restrict__ pb2,
           const float* __restrict__ row1, const float* __restrict__ rob1,
           float* __restrict__ ws) {
    __shared__ float s_t[4 * 64];
    const int tid = threadIdx.x, widx = tid >> 6, c = tid & 63;
    float* h     = ws + WS_H;
    float* nw    = ws + WS_NW;
    float* distT = ws + WS_DISTT;
    float* TTf   = ws + WS_TT;          // float view of float2 table
    const int b = blockIdx.x;

    if (b < 1024) {
        const int w = b * 4 + widx, tbl = w >> 10, g = w & 1023;
        const float d = g * STEPF;
        float val;
        if (tbl < 3) {
            const float* W1 = pw1 + tbl * NC * DIM;
            const float* B1 = pb1 + tbl * DIM;
            const float* W2 = pw2 + tbl * DIM * DIM;
            const float* B2 = pb2 + tbl * DIM;
            float t1 = B1[c];
            for (int k = 0; k < NC; ++k) {
                float x = d - GAPF * (float)k;
                float rk = __expf(NIGAP * x * x);
                t1 = fmaf(rk, W1[k * DIM + c], t1);
            }
            s_t[widx * 64 + c] = softplus05(t1);
            __syncthreads();
            val = B2[c];
            #pragma unroll 8
            for (int k = 0; k < DIM; ++k)
                val = fmaf(s_t[widx * 64 + k], W2[k * DIM + c], val);
        } else {
            __syncthreads();            // tbl uniform per block; counts match
            val = rob1[c];
            for (int k = 0; k < NC; ++k) {
                float x = d - GAPF * (float)k;
                float rk = __expf(NIGAP * x * x);
                val = fmaf(rk, row1[(2 + k) * DIM + c], val);
            }
        }
        // paired layout: TT[g][c] = (T[g][c], T[g+1][c])
        float* TTt = TTf + tbl * G * DIM * 2;
        TTt[(g * DIM + c) * 2] = val;                       // .x of row g
        if (g > 0) TTt[((g - 1) * DIM + c) * 2 + 1] = val;  // .y of row g-1
    } else if (b < 1216) {
        const int i = (b - 1024) * 4 + widx;
        const int t = types[i];
        float hv = emb[t * DIM + c];
        h[i * DIM + c] = hv;
        s_t[widx * 64 + c] = hv;
        __syncthreads();
        float acc = 0.0f;
        #pragma unroll 8
        for (int k = 0; k < DIM; ++k)
            acc = fmaf(s_t[widx * 64 + k], w1all[k * DIM + c], acc);
        nw[i * DIM + c] = acc;
    } else {
        const int idx = (b - 1216) * 256 + tid;      // < 768*768
        const int j = idx / NATOMS, i = idx - j * NATOMS;
        distT[idx] = (i == j) ? 0.0f : dist[i * NM1 + (j - (j > i))];
    }
}

// ============ edge aggregation via table lerp ============
// block = (jgroup of 4 dests) x (q chunk of 96 sources); wave widx -> dest
// j = jg*4+widx; all 4 waves share the LDS-staged nw chunk.
__global__ __launch_bounds__(256)
void k_edge(const float2* __restrict__ TTl, const float* __restrict__ distT,
            const float* __restrict__ nw, float* __restrict__ aggp) {
    __shared__ __align__(16) float s_nw[96 * DIM];   // 24 KB
    __shared__ float2 s_kf[4][96];                   // (row byte offset, frac)
    const int tid = threadIdx.x, widx = tid >> 6, c = tid & 63;
    const int jg = blockIdx.x >> 3, q = blockIdx.x & 7;
    const int j = jg * 4 + widx, ibase = q * 96;

    // stage 96 nw rows, coalesced float4
    {
        const float4* s4 = (const float4*)(nw + ibase * DIM);
        float4* d4 = (float4*)s_nw;
        #pragma unroll
        for (int r = 0; r < 6; ++r) d4[tid + r * 256] = s4[tid + r * 256];
    }
    // preload k/f for this wave's 96 edges (distT row j, coalesced)
    {
        float d = distT[j * NATOMS + ibase + c];
        float pos = d * INVSTEP;
        int kk = (int)pos;
        s_kf[widx][c] = make_float2(__int_as_float(kk * 512), pos - (float)kk);
        if (c < 32) {
            float d2 = distT[j * NATOMS + ibase + 64 + c];
            float pos2 = d2 * INVSTEP;
            int k2 = (int)pos2;
            s_kf[widx][64 + c] = make_float2(__int_as_float(k2 * 512), pos2 - (float)k2);
        }
    }
    __syncthreads();

    const char* TTb = (const char*)TTl + c * 8;
    float csum = 0.0f;
    #pragma unroll 4
    for (int it = 0; it < 96; ++it) {
        float2 kf = s_kf[widx][it];
        float2 tt = *(const float2*)(TTb + __float_as_int(kf.x));
        float e = fmaf(kf.y, tt.y - tt.x, tt.x);
        csum = fmaf(e, s_nw[it * DIM + c], csum);
    }
    // remove the fake i==j contribution (distT diag = 0 -> well-defined e)
    const int jq = j - ibase;
    if (jq >= 0 && jq < 96) {
        float2 kf = s_kf[widx][jq];
        float2 tt = *(const float2*)(TTb + __float_as_int(kf.x));
        float e = fmaf(kf.y, tt.y - tt.x, tt.x);
        csum -= e * s_nw[jq * DIM + c];
    }
    aggp[(q * NATOMS + j) * DIM + c] = csum;
}

// ============ node update (+ fused next-layer nodew OR atom_update) ============
__global__ __launch_bounds__(64)
void k_upd(const float* __restrict__ aggp,
           const float* __restrict__ qw1, const float* __restrict__ qb1,
           const float* __restrict__ qw2, const float* __restrict__ qb2,
           float* __restrict__ h,
           const float* __restrict__ wnext, float* __restrict__ nw,
           const float* __restrict__ auw1, const float* __restrict__ aub1,
           const float* __restrict__ auw2, const float* __restrict__ aub2,
           float* __restrict__ ha, int last) {
    __shared__ float sa[64], ss[64], sh[64];
    const int i = blockIdx.x, c = threadIdx.x;
    float a = 0.0f;
    #pragma unroll
    for (int qq = 0; qq < 8; ++qq) a += aggp[(qq * NATOMS + i) * DIM + c];
    sa[c] = a;
    __syncthreads();
    float t = qb1[c];
    #pragma unroll 8
    for (int k = 0; k < DIM; ++k) t = fmaf(sa[k], qw1[k * DIM + c], t);
    ss[c] = softplus05(t);
    __syncthreads();
    float o = qb2[c];
    #pragma unroll 8
    for (int k = 0; k < DIM; ++k) o = fmaf(ss[k], qw2[k * DIM + c], o);
    float hn = h[i * DIM + c] + o;
    h[i * DIM + c] = hn;
    sh[c] = hn;
    __syncthreads();
    if (!last) {
        float v = 0.0f;
        #pragma unroll 8
        for (int k = 0; k < DIM; ++k) v = fmaf(sh[k], wnext[k * DIM + c], v);
        nw[i * DIM + c] = v;
    } else {
        float t2 = aub1[c];
        #pragma unroll 8
        for (int k = 0; k < DIM; ++k) t2 = fmaf(sh[k], auw1[k * DIM + c], t2);
        t2 = ((t2 > 20.0f) ? t2 : __logf(1.0f + __expf(t2))) - LN2F;
        float v = t2 * auw2[c];
        #pragma unroll
        for (int s = 32; s > 0; s >>= 1) v += __shfl_down(v, s, 64);
        if (c == 0) ha[i] = v + aub2[0];
    }
}

// ============ readout: table lerp + rank-2 ha terms + relu + 64x2 + softmax ============
__global__ __launch_bounds__(256)
void k_ro(const float* __restrict__ dist, const int* __restrict__ src,
          const int* __restrict__ dst, const float* __restrict__ ha,
          const float2* __restrict__ TTro,
          const float* __restrict__ row1, const float* __restrict__ row2,
          const float* __restrict__ rob2, float* __restrict__ out) {
    __shared__ float4 s_pre[4][64];
    __shared__ float s_h[4][64 * 65];
    __shared__ float s_w2[128];
    const int tid = threadIdx.x, widx = tid >> 6, c = tid & 63;
    const int base = (blockIdx.x * 4 + widx) * 64;
    if (tid < 128) s_w2[tid] = row2[tid];
    {
        int eg = base + c;
        float d = dist[eg];
        float pos = d * INVSTEP;
        int kk = (int)pos;
        float fa = ha[src[eg]], fb = ha[dst[eg]];
        s_pre[widx][c] = make_float4(__int_as_float(kk * 512), pos - (float)kk, fa, fb);
    }
    __syncthreads();
    const char* TTb = (const char*)TTro + c * 8;
    const float wa = row1[c], wb = row1[DIM + c];
    #pragma unroll 2
    for (int e = 0; e < 64; ++e) {
        float4 p = s_pre[widx][e];
        float2 tt = *(const float2*)(TTb + __float_as_int(p.x));
        float hv = fmaf(p.y, tt.y - tt.x, tt.x);
        hv = fmaf(p.z, wa, hv);
        hv = fmaf(p.w, wb, hv);
        s_h[widx][e * 65 + c] = fmaxf(hv, 0.0f);
    }
    __syncthreads();
    float l0 = rob2[0], l1 = rob2[1];
    #pragma unroll 8
    for (int k = 0; k < DIM; ++k) {
        float hv = s_h[widx][c * 65 + k];
        l0 = fmaf(hv, s_w2[2 * k], l0);
        l1 = fmaf(hv, s_w2[2 * k + 1], l1);
    }
    float m = fmaxf(l0, l1);
    float e0 = __expf(l0 - m), e1 = __expf(l1 - m);
    float inv = 1.0f / (e0 + e1);
    ((float2*)out)[base + c] = make_float2(e0 * inv, e1 * inv);
}

extern "C" void kernel_launch(void* const* d_in, const int* in_sizes, int n_in,
                              void* d_out, int out_size, void* d_ws, size_t ws_size,
                              hipStream_t stream) {
    const int*   types = (const int*)d_in[0];
    const float* dist  = (const float*)d_in[1];
    const int*   srcI  = (const int*)d_in[2];
    const int*   dstI  = (const int*)d_in[3];
    const float* emb   = (const float*)d_in[4];
    const float* w1    = (const float*)d_in[5];
    const float* pw1   = (const float*)d_in[6];
    const float* pb1   = (const float*)d_in[7];
    const float* pw2   = (const float*)d_in[8];
    const float* pb2   = (const float*)d_in[9];
    const float* qw1   = (const float*)d_in[10];
    const float* qb1   = (const float*)d_in[11];
    const float* qw2   = (const float*)d_in[12];
    const float* qb2   = (const float*)d_in[13];
    const float* auw1  = (const float*)d_in[14];
    const float* aub1  = (const float*)d_in[15];
    const float* auw2  = (const float*)d_in[16];
    const float* aub2  = (const float*)d_in[17];
    const float* row1  = (const float*)d_in[18];
    const float* rob1  = (const float*)d_in[19];
    const float* row2  = (const float*)d_in[20];
    const float* rob2  = (const float*)d_in[21];

    float* ws = (float*)d_ws;
    const float2* TT = (const float2*)(ws + WS_TT);

    k_pre<<<3520, 256, 0, stream>>>(types, dist, emb, w1, pw1, pb1, pw2, pb2,
                                    row1, rob1, ws);
    for (int l = 0; l < 3; ++l) {
        k_edge<<<1536, 256, 0, stream>>>(TT + l * G * DIM, ws + WS_DISTT,
                                         ws + WS_NW, ws + WS_AGGP);
        k_upd<<<768, 64, 0, stream>>>(ws + WS_AGGP,
            qw1 + l * DIM * DIM, qb1 + l * DIM,
            qw2 + l * DIM * DIM, qb2 + l * DIM,
            ws + WS_H,
            (l < 2) ? (w1 + (l + 1) * DIM * DIM) : w1, ws + WS_NW,
            auw1, aub1, auw2, aub2, ws + WS_HA, (l == 2) ? 1 : 0);
    }
    k_ro<<<2301, 256, 0, stream>>>(dist, srcI, dstI, ws + WS_HA, TT + 3 * G * DIM,
                                   row1, row2, rob2, (float*)d_out);
}